// Round 12
// baseline (6138.768 us; speedup 1.0000x reference)
//
#include <hip/hip_runtime.h>

typedef _Float16 half8 __attribute__((ext_vector_type(8)));
typedef float f32x4 __attribute__((ext_vector_type(4)));

#define GRIDN 256   // 192 workers + 64 copy-helpers; 1 block/CU => exactly 32 blocks/XCD
#define NTICKS 514
#define TT 512
#define HH 1024

// staging geometry (elements of _Float16)
#define SLOT_E 327680u           // 640 KiB per slot: A1h(65536) + A2v(131072) + A3v(131072)
#define XCD_E  (2u * SLOT_E)     // parity double-buffer

// MFMA, B operand in AGPR ("a") — for the pinned weight units.
#define MFMA_F16_AB(acc_, a_, b_) \
  asm("v_mfma_f32_16x16x32_f16 %0, %1, %2, %0" : "+v"(acc_) : "v"(a_), "a"(b_))
// MFMA, B operand in arch VGPR ("v") — for LDS-staged weight units.
#define MFMA_F16_AV(acc_, a_, b_) \
  asm("v_mfma_f32_16x16x32_f16 %0, %1, %2, %0" : "+v"(acc_) : "v"(a_), "v"(b_))

// Tie-copy a loaded value into an AGPR-class vreg whose DEF is an inline asm
// (non-rematerializable) — keeps the weight slice resident across ticks.
#define PIN_AGPR(dst_, src_) asm("" : "=a"(dst_) : "0"(src_))

__device__ __forceinline__ int get_xcd() {
  int x;
  asm("s_getreg_b32 %0, hwreg(HW_REG_XCC_ID)" : "=s"(x));
  return x & 7;
}

__device__ __forceinline__ int kfrag(int l, int j) {
  return ((j >> 2) << 4) + (((l >> 4) & 3) << 2) + (j & 3);
}

__device__ __forceinline__ size_t fragoff(int m, int k, int KBv) {
  int rt = m >> 4, mm = m & 15, kb = k >> 5, kk = k & 31;
  int lp = mm | ((kk & 12) << 2);
  int jp = ((kk >> 4) << 2) | (kk & 3);
  return ((size_t)(rt * KBv + kb) * 512) + (size_t)lp * 8 + jp;
}

__device__ __forceinline__ float sigmoidf_(float x) { return 1.0f / (1.0f + __expf(-x)); }
__device__ __forceinline__ float tanhf_(float x)    { return 2.0f / (1.0f + __expf(-2.0f * x)) - 1.0f; }

// ---------------- weight pack: W[k][4096] -> frag layout [cg][kb][gate][lane*8+j] (f16) ---------
__global__ __launch_bounds__(256) void pack_b_kernel(const float* __restrict__ W,
                                                     _Float16* __restrict__ dst, int KB) {
  int e = blockIdx.x * 256 + threadIdx.x;
  int total = 64 * KB * 4 * 512;
  if (e >= total) return;
  int j = e & 7, l = (e >> 3) & 63, nt = (e >> 9) & 3;
  int tmp = e >> 11;
  int kb = tmp % KB, cg = tmp / KB;
  int k = kb * 32 + kfrag(l, j);
  int col = nt * 1024 + cg * 16 + (l & 15);
  dst[e] = (_Float16)W[(size_t)k * 4096 + col];
}

// ---------------- x pack: struct[b][t][d] -> frag layout [t][rt][kb][lane*8+j] (f16) ------------
__global__ __launch_bounds__(256) void pack_x_kernel(const float* __restrict__ x,
                                                     _Float16* __restrict__ dst) {
  int e = blockIdx.x * 256 + threadIdx.x;
  if (e >= TT * 4 * 8 * 512) return;
  int j = e & 7, l = (e >> 3) & 63;
  int tmp = e >> 9;
  int kb = tmp & 7; tmp >>= 3;
  int rt = tmp & 3; int t = tmp >> 2;
  int b = rt * 16 + (l & 15);
  int d = kb * 32 + kfrag(l, j);
  dst[e] = (_Float16)x[((size_t)b * TT + t) * 256 + d];
}

// ---------------- grid barrier: 8 padded monotonic counters, leaderless, NO cache fences --------
__device__ __forceinline__ void grid_barrier(unsigned* bar, int tick) {
  asm volatile("s_waitcnt vmcnt(0)" ::: "memory");  // drain own write-through stores
  __syncthreads();
  if (threadIdx.x == 0)
    __hip_atomic_fetch_add(&bar[32 * (blockIdx.x & 7)], 1u, __ATOMIC_RELAXED,
                           __HIP_MEMORY_SCOPE_AGENT);
  if (threadIdx.x < 64) {
    const unsigned target = (unsigned)(tick + 1) * 32u;  // 256/8 arrivals per counter
    for (;;) {
      unsigned v = target;
      if (threadIdx.x < 8)
        v = __hip_atomic_load(&bar[32 * threadIdx.x], __ATOMIC_RELAXED,
                              __HIP_MEMORY_SCOPE_AGENT);
      if (__all(v >= target)) break;
      __builtin_amdgcn_s_sleep(2);
    }
  }
  __syncthreads();
}

// ---------------- per-tick copy: global panels (L3) -> this XCD's staging (L2) ------------------
// rank in [0,32): 5 static chunks of 4 KiB each (160 chunks = A1h 32 + A2v 64 + A3v 64).
// Loads bypass (sc0 sc1, fresh from L3); stores cached -> fresh DIRTY lines in this XCD's L2.
__device__ __forceinline__ void copy_phase(const _Float16* A1, const _Float16* A2,
                                           const _Float16* A3, _Float16* stg,
                                           int rank, int xcd, int rpar, int tid,
                                           unsigned* stagectr) {
  const int c0 = rank * 5;
  if (c0 + 4 < 160) {  // guard (always true when XCC_ID behaves: rank<32)
    half8 v0, v1, v2, v3, v4;
    auto srcp = [&](int c) -> const _Float16* {
      if (c < 32) return A1 + (size_t)rpar * 65536 + (size_t)c * 2048 + tid * 8;
      if (c < 96) return A2 + (size_t)rpar * 131072 + (size_t)(c - 32) * 2048 + tid * 8;
      return A3 + (size_t)rpar * 131072 + (size_t)(c - 96) * 2048 + tid * 8;
    };
    _Float16* dst = stg + (size_t)xcd * XCD_E + (size_t)rpar * SLOT_E +
                    (size_t)c0 * 2048 + tid * 8;
#define CPLD(vv, cc) \
  asm volatile("global_load_dwordx4 %0, %1, off sc0 sc1" : "=v"(vv) : "v"(srcp(cc)))
    CPLD(v0, c0); CPLD(v1, c0 + 1); CPLD(v2, c0 + 2); CPLD(v3, c0 + 3); CPLD(v4, c0 + 4);
#undef CPLD
    asm volatile("s_waitcnt vmcnt(4)" ::: "memory");
    *(half8*)(dst + 0 * 2048) = v0;
    asm volatile("s_waitcnt vmcnt(4)" ::: "memory");
    *(half8*)(dst + 1 * 2048) = v1;
    asm volatile("s_waitcnt vmcnt(4)" ::: "memory");
    *(half8*)(dst + 2 * 2048) = v2;
    asm volatile("s_waitcnt vmcnt(4)" ::: "memory");
    *(half8*)(dst + 3 * 2048) = v3;
    asm volatile("s_waitcnt vmcnt(4)" ::: "memory");
    *(half8*)(dst + 4 * 2048) = v4;
  }
  asm volatile("s_waitcnt vmcnt(0)" ::: "memory");  // stores resident in this XCD's L2
  __syncthreads();
  if (tid == 0)
    __hip_atomic_fetch_add(&stagectr[32 * xcd], 1u, __ATOMIC_RELAXED,
                           __HIP_MEMORY_SCOPE_AGENT);
}

// ---------------- helper block: copy + barriers only --------------------------------------------
__device__ __forceinline__ void run_helper(const _Float16* A1, const _Float16* A2,
                                           const _Float16* A3, _Float16* stg,
                                           unsigned* stagectr, unsigned* bar,
                                           int xcd, int rank) {
  for (int tick = 0; tick < NTICKS; ++tick) {
    copy_phase(A1, A2, A3, stg, rank, xcd, (tick & 1) ^ 1, threadIdx.x, stagectr);
    if (tick < NTICKS - 1) grid_barrier(bar, tick);
  }
}

// ---------------- persistent pipelined cell loop --------------------------------------------
// Weights: UA units AGPR-pinned + rest LDS. Producers bypass-publish h to L3 (r8-proven).
// Consumers read the per-XCD L2 staging with sc0 (L1-bypass) loads, 7-deep counted pipeline.
template <int CELL, int KBW, int AKB, int UA>
__device__ __forceinline__ void run_cell(float (*red)[16][64][4],
                                         _Float16 (*wlds)[20][512],
                                         const _Float16* __restrict__ Bf,
                                         const _Float16* __restrict__ Ax,
                                         const _Float16* A1, const _Float16* A2,
                                         const _Float16* A3, _Float16* stg,
                                         const float* __restrict__ bias,
                                         float* __restrict__ h3out, unsigned* bar,
                                         unsigned* stagectr, int xcd, int rank) {
  const int cg   = blockIdx.x & 63;
  const int tid  = threadIdx.x;
  const int warp = tid >> 6;
  const int lane = tid & 63;
  const int KBTOT = (CELL == 0) ? 40 : 64;
  const int kb0   = warp * KBW;
  const unsigned POFF = (CELL == 0) ? 0u : (CELL == 1) ? 65536u : 196608u;

  _Float16* Aown = (CELL == 0) ? (_Float16*)A1 : (CELL == 1) ? (_Float16*)A2 : (_Float16*)A3;
  _Float16* Anext = (CELL == 0) ? (_Float16*)A2 : (CELL == 1) ? (_Float16*)A3 : nullptr;

  const int m0    = tid >> 3;          // 0..31
  const int colc0 = (tid & 7) * 2;     // 0,2,..,14
  float bv2[2][4];
#pragma unroll
  for (int j = 0; j < 2; ++j)
#pragma unroll
    for (int g = 0; g < 4; ++g) bv2[j][g] = bias[g * HH + cg * 16 + colc0 + j];

  const _Float16* Bbase = Bf + (size_t)cg * KBTOT * 4 * 512 + (size_t)lane * 8;

  // ---- stage overflow weight units into LDS (once) ----
  if (UA < 4 * KBW) {
#pragma unroll
    for (int u = UA; u < 4 * KBW; ++u) {
      int kk2 = u >> 2, nt2 = u & 3;
      *(half8*)&wlds[warp][u - UA][lane * 8] =
          *(const half8*)(Bbase + ((size_t)(kb0 + kk2) * 4 + nt2) * 512);
    }
  }

  // ---- pin the first UA units in AGPRs ----
  half8 wa[UA];
#pragma unroll
  for (int u = 0; u < UA; ++u) {
    int kk2 = u >> 2, nt2 = u & 3;
    half8 v = *(const half8*)(Bbase + ((size_t)(kb0 + kk2) * 4 + nt2) * 512);
    PIN_AGPR(wa[u], v);
  }

  // ---- persistent cell state in registers: 4 cells/thread ----
  float cs[2][2] = {{0.f, 0.f}, {0.f, 0.f}};
  float hs[2][2] = {{0.f, 0.f}, {0.f, 0.f}};

  for (int tick = 0; tick < NTICKS; ++tick) {
    const int wpar = tick & 1, rpar = wpar ^ 1;

    // ---- copy my 5 chunks into this XCD's staging, then wait for all 32 same-XCD copiers ----
    copy_phase(A1, A2, A3, stg, rank, xcd, rpar, tid, stagectr);
    if (tid == 0) {
      const unsigned tgt = 32u * (unsigned)(tick + 1);
      while (__hip_atomic_load(&stagectr[32 * xcd], __ATOMIC_RELAXED,
                               __HIP_MEMORY_SCOPE_AGENT) < tgt)
        __builtin_amdgcn_s_sleep(1);
    }
    __syncthreads();

    const int t = tick - CELL;
    if (t >= 0 && t < TT) {
      const _Float16* As = stg + (size_t)xcd * XCD_E + (size_t)rpar * SLOT_E + POFF +
                           (size_t)lane * 8;
      const _Float16* Axt = Ax + (size_t)t * 4 * 8 * 512 + (size_t)lane * 8;

      auto aptr = [&](int kk, int rt) -> const _Float16* {
        int kb = kb0 + kk;
        if (CELL == 0 && kb >= 32) return Axt + ((size_t)rt * 8 + (kb - 32)) * 512;
        return As + ((size_t)rt * AKB + kb) * 512;
      };

      half8 av[8][4];  // ring of 8, 7 steps in flight
      f32x4 acc[4][4];
#pragma unroll
      for (int a = 0; a < 4; ++a)
#pragma unroll
        for (int b2 = 0; b2 < 4; ++b2) acc[a][b2] = (f32x4){0.f, 0.f, 0.f, 0.f};

// sc0 only: bypass L1, HIT this XCD's L2 (fresh dirty lines installed by copy_phase)
#define ISSUE4(kk)                                                    \
  {                                                                   \
    _Pragma("unroll") for (int rt = 0; rt < 4; ++rt)                  \
        asm volatile("global_load_dwordx4 %0, %1, off sc0"            \
                     : "=v"(av[(kk) & 7][rt])                         \
                     : "v"(aptr((kk), rt)));                          \
  }

#define STEP(kk)                                                               \
  if constexpr ((kk) < KBW) {                                                  \
    if constexpr ((kk) + 7 < KBW) ISSUE4((kk) + 7);                            \
    asm volatile("s_waitcnt vmcnt(%0)" ::                                      \
                     "n"((kk) + 7 < KBW ? 28 : (KBW - 1 - (kk)) * 4)           \
                 : "memory");                                                  \
    __builtin_amdgcn_sched_barrier(0);                                         \
    _Pragma("unroll") for (int nt = 0; nt < 4; ++nt) {                         \
      const int u = (kk)*4 + nt;                                               \
      if (u < UA) {                                                            \
        _Pragma("unroll") for (int rt = 0; rt < 4; ++rt)                       \
            MFMA_F16_AB(acc[rt][nt], av[(kk) & 7][rt], wa[u < UA ? u : 0]);    \
      } else {                                                                 \
        half8 bw =                                                             \
            *(const half8*)&wlds[warp][(u >= UA ? u - UA : 0)][lane * 8];      \
        _Pragma("unroll") for (int rt = 0; rt < 4; ++rt)                       \
            MFMA_F16_AV(acc[rt][nt], av[(kk) & 7][rt], bw);                    \
      }                                                                        \
    }                                                                          \
  }

      ISSUE4(0); ISSUE4(1); ISSUE4(2); ISSUE4(3); ISSUE4(4); ISSUE4(5); ISSUE4(6);
      STEP(0)  STEP(1)  STEP(2)  STEP(3)  STEP(4)  STEP(5)  STEP(6)  STEP(7)
      STEP(8)  STEP(9)  STEP(10) STEP(11) STEP(12) STEP(13) STEP(14) STEP(15)
#undef ISSUE4
#undef STEP

      // guard asm-MFMA -> DS read-after-write
      asm volatile("s_nop 7\n\ts_nop 7");

      // K-split reduction across the 4 warps via LDS
#pragma unroll
      for (int rt = 0; rt < 4; ++rt)
#pragma unroll
        for (int nt = 0; nt < 4; ++nt)
          *(f32x4*)&red[warp][rt * 4 + nt][lane][0] = acc[rt][nt];
      __syncthreads();

      // elementwise: 4 cells/thread (2 m x 2 adjacent cols), state in registers
#pragma unroll
      for (int e = 0; e < 2; ++e) {
        const int m = m0 + e * 32;
        const int rt4 = (m >> 4) * 4, lc_hi = ((m & 15) >> 2) << 4, rr = m & 3;
        float hnf[2];
        union { _Float16 h[2]; unsigned u; } pk;
#pragma unroll
        for (int j = 0; j < 2; ++j) {
          const int lc = (colc0 + j) | lc_hi;
          float pre[4];
#pragma unroll
          for (int g = 0; g < 4; ++g)
            pre[g] = red[0][rt4 + g][lc][rr] + red[1][rt4 + g][lc][rr] +
                     red[2][rt4 + g][lc][rr] + red[3][rt4 + g][lc][rr] + bv2[j][g];
          float sf = sigmoidf_(pre[0]), si = sigmoidf_(pre[1]), so = sigmoidf_(pre[2]);
          float tg = tanhf_(pre[3]);
          float c_old = cs[e][j], h_old = hs[e][j];
          float c0 = sf * c_old + si * tg;
          float h0 = so * tanhf_(c0);
          float cn = 0.9f * c0 + 0.1f * c_old;
          float hn = 0.9f * h0 + 0.1f * h_old;
          cs[e][j] = cn;
          hs[e][j] = hn;
          hnf[j] = hn;
          pk.h[j] = (_Float16)hn;
        }
        const int hcol0 = cg * 16 + colc0;
        {
          size_t off = (size_t)wpar * 4 * AKB * 512 + fragoff(m, hcol0, AKB);
          __hip_atomic_store((unsigned*)(Aown + off), pk.u, __ATOMIC_RELAXED,
                             __HIP_MEMORY_SCOPE_AGENT);
        }
        if (CELL < 2) {
          size_t off = (size_t)wpar * 4 * 64 * 512 + fragoff(m, 1024 + hcol0, 64);
          __hip_atomic_store((unsigned*)(Anext + off), pk.u, __ATOMIC_RELAXED,
                             __HIP_MEMORY_SCOPE_AGENT);
        }
        if (CELL == 2 && t == TT - 1) {
          h3out[m * HH + hcol0]     = hnf[0];
          h3out[m * HH + hcol0 + 1] = hnf[1];
        }
      }
    }

    if (tick < NTICKS - 1) grid_barrier(bar, tick);
  }
}

__global__ __launch_bounds__(256, 1) void lstm_coop(
    const _Float16* __restrict__ Bf1, const _Float16* __restrict__ Bf2,
    const _Float16* __restrict__ Bf3, const _Float16* __restrict__ Ax,
    _Float16* A1h, _Float16* A2v, _Float16* A3v, _Float16* stg, float* h3,
    const float* __restrict__ bb1, const float* __restrict__ bb2, const float* __restrict__ bb3,
    unsigned* bar, unsigned* xcdcnt, unsigned* stagectr) {
  __shared__ float red[4][16][64][4];        // 64 KiB exchange
  __shared__ _Float16 wlds[4][20][512];      // 80 KiB LDS-resident weight units
  __shared__ int sh_xcd, sh_rank;
  if (threadIdx.x == 0) {
    int x = get_xcd();
    sh_xcd = x;
    sh_rank = (int)__hip_atomic_fetch_add(&xcdcnt[32 * x], 1u, __ATOMIC_RELAXED,
                                          __HIP_MEMORY_SCOPE_AGENT);
  }
  __syncthreads();
  const int xcd = sh_xcd, rank = sh_rank;

  const int cell = blockIdx.x >> 6;
  if (cell == 0)
    run_cell<0, 10, 32, 40>(red, wlds, Bf1, Ax, A1h, A2v, A3v, stg, bb1, nullptr, bar,
                            stagectr, xcd, rank);
  else if (cell == 1)
    run_cell<1, 16, 64, 44>(red, wlds, Bf2, Ax, A1h, A2v, A3v, stg, bb2, nullptr, bar,
                            stagectr, xcd, rank);
  else if (cell == 2)
    run_cell<2, 16, 64, 44>(red, wlds, Bf3, Ax, A1h, A2v, A3v, stg, bb3, h3, bar,
                            stagectr, xcd, rank);
  else
    run_helper(A1h, A2v, A3v, stg, stagectr, bar, xcd, rank);
}

// ---------------- final FC + ELU ----------------------------------------------------------------
__global__ __launch_bounds__(256) void fc_kernel(const float* __restrict__ h3,
                                                 const float* __restrict__ fcw,
                                                 const float* __restrict__ fcb,
                                                 float* __restrict__ out) {
  int wid = (blockIdx.x * 256 + threadIdx.x) >> 6;
  int lane = threadIdx.x & 63;
  if (wid >= 64 * 128) return;
  int b = wid >> 7, cc = wid & 127;
  float s = 0.f;
#pragma unroll
  for (int i = 0; i < 16; ++i) {
    int k = i * 64 + lane;
    s += h3[b * HH + k] * fcw[cc * HH + k];
  }
#pragma unroll
  for (int o = 32; o; o >>= 1) s += __shfl_xor(s, o, 64);
  if (lane == 0) {
    s += fcb[cc];
    out[b * 128 + cc] = s > 0.f ? s : (__expf(s) - 1.0f);
  }
}

extern "C" void kernel_launch(void* const* d_in, const int* in_sizes, int n_in,
                              void* d_out, int out_size, void* d_ws, size_t ws_size,
                              hipStream_t stream) {
  const float* xs  = (const float*)d_in[0];
  const float* W1  = (const float*)d_in[1];
  const float* b1  = (const float*)d_in[2];
  const float* W2  = (const float*)d_in[3];
  const float* b2  = (const float*)d_in[4];
  const float* W3  = (const float*)d_in[5];
  const float* b3  = (const float*)d_in[6];
  const float* fcw = (const float*)d_in[7];
  const float* fcb = (const float*)d_in[8];
  float* out = (float*)d_out;

  char* p = (char*)d_ws;
  auto alloc = [&](size_t bytes) {
    char* r = p;
    p += (bytes + 255) & ~(size_t)255;
    return r;
  };

  // ---- zero-init region (re-zeroed every replay) ----
  char* zbase = p;
  _Float16* A1h = (_Float16*)alloc((size_t)2 * 4 * 32 * 512 * 2);
  _Float16* A2v = (_Float16*)alloc((size_t)2 * 4 * 64 * 512 * 2);
  _Float16* A3v = (_Float16*)alloc((size_t)2 * 4 * 64 * 512 * 2);
  unsigned* bar      = (unsigned*)alloc(1024);
  unsigned* xcdcnt   = (unsigned*)alloc(1024);
  unsigned* stagectr = (unsigned*)alloc(1024);
  size_t zbytes = (size_t)(p - zbase);

  // ---- fully-overwritten region ----
  float* h3 = (float*)alloc((size_t)64 * 1024 * 4);
  _Float16* Bf1 = (_Float16*)alloc((size_t)64 * 40 * 4 * 512 * 2);
  _Float16* Bf2 = (_Float16*)alloc((size_t)64 * 64 * 4 * 512 * 2);
  _Float16* Bf3 = (_Float16*)alloc((size_t)64 * 64 * 4 * 512 * 2);
  _Float16* Axp = (_Float16*)alloc((size_t)TT * 4 * 8 * 512 * 2);
  _Float16* stg = (_Float16*)alloc((size_t)8 * XCD_E * 2);  // 10.5 MiB per-XCD staging

  (void)hipMemsetAsync(zbase, 0, zbytes, stream);

  {
    int tot1 = 64 * 40 * 4 * 512, tot23 = 64 * 64 * 4 * 512;
    pack_b_kernel<<<(tot1 + 255) / 256, 256, 0, stream>>>(W1, Bf1, 40);
    pack_b_kernel<<<(tot23 + 255) / 256, 256, 0, stream>>>(W2, Bf2, 64);
    pack_b_kernel<<<(tot23 + 255) / 256, 256, 0, stream>>>(W3, Bf3, 64);
    int totx = TT * 4 * 8 * 512;
    pack_x_kernel<<<(totx + 255) / 256, 256, 0, stream>>>(xs, Axp);
  }

  lstm_coop<<<GRIDN, 256, 0, stream>>>(Bf1, Bf2, Bf3, Axp, A1h, A2v, A3v, stg, h3,
                                       b1, b2, b3, bar, xcdcnt, stagectr);

  fc_kernel<<<(64 * 128 * 64 + 255) / 256, 256, 0, stream>>>(h3, fcw, fcb, out);
}

// Round 15
// 3889.465 us; speedup vs baseline: 1.5783x; 1.5783x over previous
//
#include <hip/hip_runtime.h>

typedef _Float16 half8 __attribute__((ext_vector_type(8)));
typedef float f32x4 __attribute__((ext_vector_type(4)));

#define GRIDN 192
#define NTICKS 514
#define TT 512
#define HH 1024

// MFMA, B operand in AGPR ("a") — for the pinned weight units.
#define MFMA_F16_AB(acc_, a_, b_) \
  asm("v_mfma_f32_16x16x32_f16 %0, %1, %2, %0" : "+v"(acc_) : "v"(a_), "a"(b_))
// MFMA, B operand in arch VGPR ("v") — for LDS-staged weight units.
#define MFMA_F16_AV(acc_, a_, b_) \
  asm("v_mfma_f32_16x16x32_f16 %0, %1, %2, %0" : "+v"(acc_) : "v"(a_), "v"(b_))

// Tie-copy a loaded value into an AGPR-class vreg whose DEF is an inline asm
// (non-rematerializable) — keeps the weight slice resident across ticks.
#define PIN_AGPR(dst_, src_) asm("" : "=a"(dst_) : "0"(src_))

__device__ __forceinline__ int kfrag(int l, int j) {
  return ((j >> 2) << 4) + (((l >> 4) & 3) << 2) + (j & 3);
}

__device__ __forceinline__ size_t fragoff(int m, int k, int KBv) {
  int rt = m >> 4, mm = m & 15, kb = k >> 5, kk = k & 31;
  int lp = mm | ((kk & 12) << 2);
  int jp = ((kk >> 4) << 2) | (kk & 3);
  return ((size_t)(rt * KBv + kb) * 512) + (size_t)lp * 8 + jp;
}

__device__ __forceinline__ float sigmoidf_(float x) { return 1.0f / (1.0f + __expf(-x)); }
__device__ __forceinline__ float tanhf_(float x)    { return 2.0f / (1.0f + __expf(-2.0f * x)) - 1.0f; }

// ---------------- weight pack: W[k][4096] -> frag layout [cg][kb][gate][lane*8+j] (f16) ---------
__global__ __launch_bounds__(256) void pack_b_kernel(const float* __restrict__ W,
                                                     _Float16* __restrict__ dst, int KB) {
  int e = blockIdx.x * 256 + threadIdx.x;
  int total = 64 * KB * 4 * 512;
  if (e >= total) return;
  int j = e & 7, l = (e >> 3) & 63, nt = (e >> 9) & 3;
  int tmp = e >> 11;
  int kb = tmp % KB, cg = tmp / KB;
  int k = kb * 32 + kfrag(l, j);
  int col = nt * 1024 + cg * 16 + (l & 15);
  dst[e] = (_Float16)W[(size_t)k * 4096 + col];
}

// ---------------- x pack: struct[b][t][d] -> frag layout [t][rt][kb][lane*8+j] (f16) ------------
__global__ __launch_bounds__(256) void pack_x_kernel(const float* __restrict__ x,
                                                     _Float16* __restrict__ dst) {
  int e = blockIdx.x * 256 + threadIdx.x;
  if (e >= TT * 4 * 8 * 512) return;
  int j = e & 7, l = (e >> 3) & 63;
  int tmp = e >> 9;
  int kb = tmp & 7; tmp >>= 3;
  int rt = tmp & 3; int t = tmp >> 2;
  int b = rt * 16 + (l & 15);
  int d = kb * 32 + kfrag(l, j);
  dst[e] = (_Float16)x[((size_t)b * TT + t) * 256 + d];
}

// ---------------- grid barrier: 8 padded monotonic counters, leaderless, NO cache fences --------
__device__ __forceinline__ void grid_barrier(unsigned* bar, int tick) {
  asm volatile("s_waitcnt vmcnt(0)" ::: "memory");  // drain own write-through stores
  __syncthreads();
  if (threadIdx.x == 0)
    __hip_atomic_fetch_add(&bar[32 * (blockIdx.x & 7)], 1u, __ATOMIC_RELAXED,
                           __HIP_MEMORY_SCOPE_AGENT);
  if (threadIdx.x < 64) {
    const unsigned target = (unsigned)(tick + 1) * 24u;  // 192/8 arrivals per counter
    for (;;) {
      unsigned v = target;
      if (threadIdx.x < 8)
        v = __hip_atomic_load(&bar[32 * threadIdx.x], __ATOMIC_RELAXED,
                              __HIP_MEMORY_SCOPE_AGENT);
      if (__all(v >= target)) break;
      __builtin_amdgcn_s_sleep(2);
    }
  }
  __syncthreads();
}

// ---------------- persistent pipelined cell loop --------------------------------------------
// r8-proven protocol. A-loads: 16B bypass-coherent asm loads (sc0 sc1), software-pipelined
// 7 steps ahead with counted vmcnt + sched_barrier (rule #18).
template <int CELL, int KBW, int AKB, int UA>
__device__ __forceinline__ void run_cell(float (*red)[16][64][4],
                                         _Float16 (*wlds)[20][512],
                                         const _Float16* __restrict__ Bf,
                                         const _Float16* __restrict__ Ax,
                                         _Float16* Aown, _Float16* Anext,
                                         const float* __restrict__ bias,
                                         float* __restrict__ h3out, unsigned* bar) {
  const int cg   = blockIdx.x & 63;
  const int tid  = threadIdx.x;
  const int warp = tid >> 6;
  const int lane = tid & 63;
  const int KBTOT = (CELL == 0) ? 40 : 64;
  const int kb0   = warp * KBW;

  const int m0    = tid >> 3;          // 0..31
  const int colc0 = (tid & 7) * 2;     // 0,2,..,14
  float bv2[2][4];
#pragma unroll
  for (int j = 0; j < 2; ++j)
#pragma unroll
    for (int g = 0; g < 4; ++g) bv2[j][g] = bias[g * HH + cg * 16 + colc0 + j];

  const _Float16* Bbase = Bf + (size_t)cg * KBTOT * 4 * 512 + (size_t)lane * 8;

  // ---- stage overflow weight units into LDS (once) ----
  if (UA < 4 * KBW) {
#pragma unroll
    for (int u = UA; u < 4 * KBW; ++u) {
      int kk2 = u >> 2, nt2 = u & 3;
      *(half8*)&wlds[warp][u - UA][lane * 8] =
          *(const half8*)(Bbase + ((size_t)(kb0 + kk2) * 4 + nt2) * 512);
    }
  }

  // ---- pin the first UA units in AGPRs ----
  half8 wa[UA];
#pragma unroll
  for (int u = 0; u < UA; ++u) {
    int kk2 = u >> 2, nt2 = u & 3;
    half8 v = *(const half8*)(Bbase + ((size_t)(kb0 + kk2) * 4 + nt2) * 512);
    PIN_AGPR(wa[u], v);
  }

  // ---- persistent cell state in registers: 4 cells/thread ----
  float cs[2][2] = {{0.f, 0.f}, {0.f, 0.f}};
  float hs[2][2] = {{0.f, 0.f}, {0.f, 0.f}};

  for (int tick = 0; tick < NTICKS; ++tick) {
    const int t = tick - CELL;
    if (t >= 0 && t < TT) {
      const int wpar = tick & 1, rpar = wpar ^ 1;
      const _Float16* Ard = Aown + (size_t)rpar * 4 * AKB * 512 + (size_t)lane * 8;
      const _Float16* Axt = Ax + (size_t)t * 4 * 8 * 512 + (size_t)lane * 8;

      auto aptr = [&](int kk, int rt) -> const _Float16* {
        int kb = kb0 + kk;
        if (CELL == 0 && kb >= 32) return Axt + ((size_t)rt * 8 + (kb - 32)) * 512;
        return Ard + ((size_t)rt * AKB + kb) * 512;
      };

      half8 av[8][4];  // ring of 8, 7 steps in flight
      f32x4 acc[4][4];
#pragma unroll
      for (int a = 0; a < 4; ++a)
#pragma unroll
        for (int b2 = 0; b2 < 4; ++b2) acc[a][b2] = (f32x4){0.f, 0.f, 0.f, 0.f};

// issue 4 bypass-coherent 16B loads for K-step kk (in-order issue => vmcnt accounting holds)
#define ISSUE4(kk)                                                    \
  {                                                                   \
    _Pragma("unroll") for (int rt = 0; rt < 4; ++rt)                  \
        asm volatile("global_load_dwordx4 %0, %1, off sc0 sc1"        \
                     : "=v"(av[(kk) & 7][rt])                         \
                     : "v"(aptr((kk), rt)));                          \
  }

// one K-step: refill 7-ahead, counted wait for step kk, pin scheduler, 16 MFMAs
#define STEP(kk)                                                               \
  if constexpr ((kk) < KBW) {                                                  \
    if constexpr ((kk) + 7 < KBW) ISSUE4((kk) + 7);                            \
    asm volatile("s_waitcnt vmcnt(%0)" ::                                      \
                     "n"((kk) + 7 < KBW ? 28 : (KBW - 1 - (kk)) * 4)           \
                 : "memory");                                                  \
    __builtin_amdgcn_sched_barrier(0);                                         \
    _Pragma("unroll") for (int nt = 0; nt < 4; ++nt) {                         \
      const int u = (kk)*4 + nt;                                               \
      if (u < UA) {                                                            \
        _Pragma("unroll") for (int rt = 0; rt < 4; ++rt)                       \
            MFMA_F16_AB(acc[rt][nt], av[(kk) & 7][rt], wa[u < UA ? u : 0]);    \
      } else {                                                                 \
        half8 bw =                                                             \
            *(const half8*)&wlds[warp][(u >= UA ? u - UA : 0)][lane * 8];      \
        _Pragma("unroll") for (int rt = 0; rt < 4; ++rt)                       \
            MFMA_F16_AV(acc[rt][nt], av[(kk) & 7][rt], bw);                    \
      }                                                                        \
    }                                                                          \
  }

      // prologue: 7 steps in flight
      ISSUE4(0); ISSUE4(1); ISSUE4(2); ISSUE4(3); ISSUE4(4); ISSUE4(5); ISSUE4(6);
      STEP(0)  STEP(1)  STEP(2)  STEP(3)  STEP(4)  STEP(5)  STEP(6)  STEP(7)
      STEP(8)  STEP(9)  STEP(10) STEP(11) STEP(12) STEP(13) STEP(14) STEP(15)
#undef ISSUE4
#undef STEP

      // guard asm-MFMA -> DS read-after-write
      asm volatile("s_nop 7\n\ts_nop 7");

      // K-split reduction across the 4 warps via LDS
#pragma unroll
      for (int rt = 0; rt < 4; ++rt)
#pragma unroll
        for (int nt = 0; nt < 4; ++nt)
          *(f32x4*)&red[warp][rt * 4 + nt][lane][0] = acc[rt][nt];
      __syncthreads();

      // elementwise: 4 cells/thread (2 m x 2 adjacent cols), state in registers
#pragma unroll
      for (int e = 0; e < 2; ++e) {
        const int m = m0 + e * 32;
        const int rt4 = (m >> 4) * 4, lc_hi = ((m & 15) >> 2) << 4, rr = m & 3;
        float hnf[2];
        union { _Float16 h[2]; unsigned u; } pk;
#pragma unroll
        for (int j = 0; j < 2; ++j) {
          const int lc = (colc0 + j) | lc_hi;
          float pre[4];
#pragma unroll
          for (int g = 0; g < 4; ++g)
            pre[g] = red[0][rt4 + g][lc][rr] + red[1][rt4 + g][lc][rr] +
                     red[2][rt4 + g][lc][rr] + red[3][rt4 + g][lc][rr] + bv2[j][g];
          float sf = sigmoidf_(pre[0]), si = sigmoidf_(pre[1]), so = sigmoidf_(pre[2]);
          float tg = tanhf_(pre[3]);
          float c_old = cs[e][j], h_old = hs[e][j];
          float c0 = sf * c_old + si * tg;
          float h0 = so * tanhf_(c0);
          float cn = 0.9f * c0 + 0.1f * c_old;
          float hn = 0.9f * h0 + 0.1f * h_old;
          cs[e][j] = cn;
          hs[e][j] = hn;
          hnf[j] = hn;
          pk.h[j] = (_Float16)hn;
        }
        const int hcol0 = cg * 16 + colc0;
        {
          size_t off = (size_t)wpar * 4 * AKB * 512 + fragoff(m, hcol0, AKB);
          __hip_atomic_store((unsigned*)(Aown + off), pk.u, __ATOMIC_RELAXED,
                             __HIP_MEMORY_SCOPE_AGENT);
        }
        if (CELL < 2) {
          size_t off = (size_t)wpar * 4 * 64 * 512 + fragoff(m, 1024 + hcol0, 64);
          __hip_atomic_store((unsigned*)(Anext + off), pk.u, __ATOMIC_RELAXED,
                             __HIP_MEMORY_SCOPE_AGENT);
        }
        if (CELL == 2 && t == TT - 1) {
          h3out[m * HH + hcol0]     = hnf[0];
          h3out[m * HH + hcol0 + 1] = hnf[1];
        }
      }
    }

    if (tick < NTICKS - 1) grid_barrier(bar, tick);
  }
}

__global__ __launch_bounds__(256, 1) void lstm_coop(
    const _Float16* __restrict__ Bf1, const _Float16* __restrict__ Bf2,
    const _Float16* __restrict__ Bf3, const _Float16* __restrict__ Ax,
    _Float16* A1h, _Float16* A2v, _Float16* A3v, float* h3,
    const float* __restrict__ bb1, const float* __restrict__ bb2, const float* __restrict__ bb3,
    unsigned* bar) {
  __shared__ float red[4][16][64][4];        // 64 KiB exchange
  __shared__ _Float16 wlds[4][20][512];      // 80 KiB LDS-resident weight units
  const int cell = blockIdx.x >> 6;
  if (cell == 0)
    run_cell<0, 10, 32, 40>(red, wlds, Bf1, Ax, A1h, A2v, bb1, nullptr, bar);
  else if (cell == 1)
    run_cell<1, 16, 64, 44>(red, wlds, Bf2, Ax, A2v, A3v, bb2, nullptr, bar);
  else
    run_cell<2, 16, 64, 44>(red, wlds, Bf3, Ax, A3v, nullptr, bb3, h3, bar);
}

// ---------------- final FC + ELU ----------------------------------------------------------------
__global__ __launch_bounds__(256) void fc_kernel(const float* __restrict__ h3,
                                                 const float* __restrict__ fcw,
                                                 const float* __restrict__ fcb,
                                                 float* __restrict__ out) {
  int wid = (blockIdx.x * 256 + threadIdx.x) >> 6;
  int lane = threadIdx.x & 63;
  if (wid >= 64 * 128) return;
  int b = wid >> 7, cc = wid & 127;
  float s = 0.f;
#pragma unroll
  for (int i = 0; i < 16; ++i) {
    int k = i * 64 + lane;
    s += h3[b * HH + k] * fcw[cc * HH + k];
  }
#pragma unroll
  for (int o = 32; o; o >>= 1) s += __shfl_xor(s, o, 64);
  if (lane == 0) {
    s += fcb[cc];
    out[b * 128 + cc] = s > 0.f ? s : (__expf(s) - 1.0f);
  }
}

extern "C" void kernel_launch(void* const* d_in, const int* in_sizes, int n_in,
                              void* d_out, int out_size, void* d_ws, size_t ws_size,
                              hipStream_t stream) {
  const float* xs  = (const float*)d_in[0];
  const float* W1  = (const float*)d_in[1];
  const float* b1  = (const float*)d_in[2];
  const float* W2  = (const float*)d_in[3];
  const float* b2  = (const float*)d_in[4];
  const float* W3  = (const float*)d_in[5];
  const float* b3  = (const float*)d_in[6];
  const float* fcw = (const float*)d_in[7];
  const float* fcb = (const float*)d_in[8];
  float* out = (float*)d_out;

  char* p = (char*)d_ws;
  auto alloc = [&](size_t bytes) {
    char* r = p;
    p += (bytes + 255) & ~(size_t)255;
    return r;
  };

  // ---- zero-init region (re-zeroed every replay) ----
  char* zbase = p;
  _Float16* A1h = (_Float16*)alloc((size_t)2 * 4 * 32 * 512 * 2);
  _Float16* A2v = (_Float16*)alloc((size_t)2 * 4 * 64 * 512 * 2);
  _Float16* A3v = (_Float16*)alloc((size_t)2 * 4 * 64 * 512 * 2);
  unsigned* bar = (unsigned*)alloc(1024);
  size_t zbytes = (size_t)(p - zbase);

  // ---- fully-overwritten region ----
  float* h3 = (float*)alloc((size_t)64 * 1024 * 4);
  _Float16* Bf1 = (_Float16*)alloc((size_t)64 * 40 * 4 * 512 * 2);
  _Float16* Bf2 = (_Float16*)alloc((size_t)64 * 64 * 4 * 512 * 2);
  _Float16* Bf3 = (_Float16*)alloc((size_t)64 * 64 * 4 * 512 * 2);
  _Float16* Axp = (_Float16*)alloc((size_t)TT * 4 * 8 * 512 * 2);

  (void)hipMemsetAsync(zbase, 0, zbytes, stream);

  {
    int tot1 = 64 * 40 * 4 * 512, tot23 = 64 * 64 * 4 * 512;
    pack_b_kernel<<<(tot1 + 255) / 256, 256, 0, stream>>>(W1, Bf1, 40);
    pack_b_kernel<<<(tot23 + 255) / 256, 256, 0, stream>>>(W2, Bf2, 64);
    pack_b_kernel<<<(tot23 + 255) / 256, 256, 0, stream>>>(W3, Bf3, 64);
    int totx = TT * 4 * 8 * 512;
    pack_x_kernel<<<(totx + 255) / 256, 256, 0, stream>>>(xs, Axp);
  }

  lstm_coop<<<GRIDN, 256, 0, stream>>>(Bf1, Bf2, Bf3, Axp, A1h, A2v, A3v, h3,
                                       b1, b2, b3, bar);

  fc_kernel<<<(64 * 128 * 64 + 255) / 256, 256, 0, stream>>>(h3, fcw, fcb, out);
}